// Round 9
// baseline (210.711 us; speedup 1.0000x reference)
//
#include <hip/hip_runtime.h>
#include <math.h>

#define B_ 4
#define D_ 32
#define H_ 192
#define W_ 192
#define HW_ (H_ * W_)

#define NT 5            // Taylor terms p = 1..5

#define TW 48           // 12 col-groups x 4 cols (b128)
#define TH 12
#define NTHR 256
#define ZCHUNK 16
#define NP (ZCHUNK + 8) // 24 staged planes; loop runs p = 0..NP+1

#define XT_H 26         // TH + 14
#define XT_COLS 62      // TW + 14
#define XT_W 68         // %4==0: b128-aligned rows
#define XT_CELLS (XT_H * XT_COLS)   // 1612
#define XT_SZ (XT_H * XT_W)         // 1768
#define NSEC 7

#define R_S 48          // row-major R[n][row][col]
#define R_H 26
#define CTERM (R_H * R_S)           // 1248
#define RWORDS (NT * CTERM)         // 6240

#define NITEM 72                    // tall-2 h items: 6 rowblocks x 12 cg
#define SCR_WORDS (2 * NITEM * 8)   // parity-dbuf merge scratch (1152)

#define SMEM_WORDS (RWORDS + 2 * XT_SZ + SCR_WORDS)   // 10928 fl = 43.7 KB

#define NTAPS (B_ * 9 * 15 * 15)

__device__ inline float4 f4fma(float c, float4 a, float4 d) {
    d.x = fmaf(c, a.x, d.x); d.y = fmaf(c, a.y, d.y);
    d.z = fmaf(c, a.z, d.z); d.w = fmaf(c, a.w, d.w);
    return d;
}
__device__ inline float4 f4add(float4 a, float4 b) {
    a.x += b.x; a.y += b.y; a.z += b.z; a.w += b.w; return a;
}
__device__ inline float rfl(float x) {
    return __int_as_float(__builtin_amdgcn_readfirstlane(__float_as_int(x)));
}

// h-conv over term range [N0,N1): tall-2 item, 16 b128 row reads per term,
// symmetric h taps, z-ring accumulate for both rows.
template <int N0, int N1>
__device__ __forceinline__ void hconv(const float* __restrict__ Rr, int hb,
                                      const float cg_[NT][8], const float cz_[NT][5],
                                      float4 acc[9][2]) {
#pragma unroll
    for (int n = N0; n < N1; ++n) {
        const float* R1 = Rr + n * CTERM + hb;
        float4 v[16];
#pragma unroll
        for (int j = 0; j < 16; ++j) v[j] = *(const float4*)&R1[j * R_S];
        float4 q0, q1;
        q0.x = cg_[n][0] * v[7].x;  q0.y = cg_[n][0] * v[7].y;
        q0.z = cg_[n][0] * v[7].z;  q0.w = cg_[n][0] * v[7].w;
        q1.x = cg_[n][0] * v[8].x;  q1.y = cg_[n][0] * v[8].y;
        q1.z = cg_[n][0] * v[8].z;  q1.w = cg_[n][0] * v[8].w;
#pragma unroll
        for (int m = 1; m <= 7; ++m) {
            float c = cg_[n][m];
            q0 = f4fma(c, f4add(v[7 - m], v[7 + m]), q0);
            q1 = f4fma(c, f4add(v[8 - m], v[8 + m]), q1);
        }
        acc[4][0] = f4fma(cz_[n][0], q0, acc[4][0]);
        acc[4][1] = f4fma(cz_[n][0], q1, acc[4][1]);
#pragma unroll
        for (int j = 1; j <= 4; ++j) {
            float cz = cz_[n][j];
            acc[4 + j][0] = f4fma(cz, q0, acc[4 + j][0]);
            acc[4 + j][1] = f4fma(cz, q1, acc[4 + j][1]);
            acc[4 - j][0] = f4fma(cz, q0, acc[4 - j][0]);
            acc[4 - j][1] = f4fma(cz, q1, acc[4 - j][1]);
        }
    }
}

__global__ __launch_bounds__(NTHR, 2)
void conv_kernel(const float* __restrict__ x,
                 const float* __restrict__ bet_xy,
                 const float* __restrict__ bet_z,
                 const float* __restrict__ alpha,
                 float* __restrict__ out) {
    __shared__ __align__(16) float smem[SMEM_WORDS];
    float* Rm  = smem;                        // [NT][R_H][R_S]
    float* xtb = smem + RWORDS;               // [2][XT_SZ]
    float* scr = smem + RWORDS + 2 * XT_SZ;   // [2][NITEM][8]
    float* red = smem;                        // alias: pre-loop only
    float* ct  = smem + 512;                  // alias: pre-loop only

    const int t  = threadIdx.x;
    const int w0 = blockIdx.x * TW;
    const int h0 = blockIdx.y * TH;
    const int bz = blockIdx.z;
    const int b  = bz & 3;
    const int z0 = (bz >> 2) * ZCHUNK;
    const float INV = 0.3989422804014327f;

    // ---- exact global sum S (deterministic, identical in every block) ----
    float local = 0.f;
#pragma unroll
    for (int s = 0; s < 32; ++s) {
        int idx = t + s * NTHR;
        if (idx < NTAPS) {
            int bb = idx / 2025;
            int r  = idx % 2025;
            int dz = r / 225;
            int r2 = r % 225;
            int dh = r2 / 15;
            int dw = r2 % 15;
            float bxy = bet_xy[bb], bzv = bet_z[bb], al = alpha[bb];
            float zd = (float)(dz - 4), hd = (float)(dh - 7), wd = (float)(dw - 7);
            float az = expf(-zd * zd / (2.f * bzv * bzv)) * (INV / bzv);
            float gh = expf(-hd * hd / (2.f * bxy * bxy)) * (INV / bxy);
            float gw = expf(-wd * wd / (2.f * bxy * bxy)) * (INV / bxy);
            local += 1.f - expf(-al * az * gh * gw);
        }
    }
    red[t] = local;
    __syncthreads();
    for (int s = 128; s > 0; s >>= 1) {
        if (t < s) red[t] += red[t + s];
        __syncthreads();
    }
    const float S = red[0];
    __syncthreads();

    // ---- own batch's coefficient table (65 values) ----
    if (t < NT * 13) {
        int n = t / 13;
        int k = t % 13;
        float bxy = bet_xy[b], bzv = bet_z[b], al = alpha[b];
        if (k < 8) {
            float d = (float)k;
            float g = expf(-d * d / (2.f * bxy * bxy)) * (INV / bxy);
            float p = g;
            for (int q = 0; q < n; ++q) p *= g;
            ct[n * 16 + k] = p;
        } else {
            float d = (float)(k - 8);
            float az = expf(-d * d / (2.f * bzv * bzv)) * (INV / bzv);
            float base = al * az;
            float p = base;
            for (int q = 0; q < n; ++q) p *= base;
            const float facs[NT] = {1.f, 2.f, 6.f, 24.f, 120.f};
            float sign = (n & 1) ? -1.f : 1.f;
            ct[n * 16 + k] = sign * p / (facs[n] * S);
        }
    }
    __syncthreads();

    // ---- hoist coefficients to wave-uniform scalars ----
    float cg_[NT][8], cz_[NT][5];
#pragma unroll
    for (int n = 0; n < NT; ++n) {
#pragma unroll
        for (int k = 0; k < 8; ++k) cg_[n][k] = rfl(ct[n * 16 + k]);
#pragma unroll
        for (int k = 0; k < 5; ++k) cz_[n][k] = rfl(ct[n * 16 + 8 + k]);
    }
    __syncthreads();   // ct/red reads done before any R/xt write

    // ---- staging descriptors (plane-invariant) ----
    const float* xb = x + (size_t)b * (D_ * HW_);
    int goff[NSEC], loff[NSEC];
#pragma unroll
    for (int k = 0; k < NSEC; ++k) {
        int i = t + k * NTHR;
        int r = i / XT_COLS, c = i - r * XT_COLS;
        int gh = h0 + r - 7, gw = w0 + c - 7;
        bool ok = (i < XT_CELLS) && gh >= 0 && gh < H_ && gw >= 0 && gw < W_;
        goff[k] = ok ? (gh * W_ + gw) : -1;
        loff[k] = (i < XT_CELLS) ? (r * XT_W + c) : (XT_SZ - 1);
    }
    // pre-stage first plane (zi = z0-4) into xt buffer 0
    {
        int zi0 = z0 - 4;
        if (zi0 >= 0) {
#pragma unroll
            for (int k = 0; k < NSEC; ++k) {
                float v = 0.f;
                if (goff[k] >= 0) v = xb[(size_t)zi0 * HW_ + goff[k]];
                xtb[loff[k]] = v;
            }
        }
    }

    // ---- per-thread roles ----
    // w-conv: row-major items over 26 rows x 12 cg; sec1 on t>=200 (items 256..311)
    const int i0r = t / 12,  i0c = t - 12 * i0r;
    const int i1  = t + 56;
    const int i1r = i1 / 12, i1c = i1 - 12 * i1r;
    const bool sec1 = (t >= 200);
    const int wb0 = i0r * XT_W + 4 * i0c, rw0 = i0r * R_S + 4 * i0c;
    const int wb1 = i1r * XT_W + 4 * i1c, rw1 = i1r * R_S + 4 * i1c;
    // h-conv: tall-2 items (rowblock q=0..5, cg=0..11), pair split by wave parity
    const int wv = t >> 6, ln = t & 63;
    const bool hA = (wv == 0) || (wv == 2 && ln < 8);   // terms 0..2
    const bool hB = (wv == 1) || (wv == 3 && ln < 8);   // terms 3..4
    const bool hact = hA || hB;
    const int hitem = (wv <= 1) ? ln : (64 + ln);       // 0..71 for active
    const int hq  = hitem / 12, hcg = hitem - 12 * hq;
    const int hb  = (2 * hq) * R_S + 4 * hcg;           // rows 2q..2q+15 via +j*R_S

    float4 acc[9][2];   // z-ring, 2 output rows per slot
#pragma unroll
    for (int k = 0; k < 9; ++k) {
        acc[k][0] = make_float4(0.f, 0.f, 0.f, 0.f);
        acc[k][1] = make_float4(0.f, 0.f, 0.f, 0.f);
    }
    float4 pend0 = make_float4(0.f, 0.f, 0.f, 0.f);
    float4 pend1 = make_float4(0.f, 0.f, 0.f, 0.f);

#pragma unroll 1
    for (int p = 0; p <= NP + 1; ++p) {
        __syncthreads();   // B1: R(plane p-1) complete; scr(parity p-1) written

        const int zi = z0 - 4 + p;
        const int zn = zi + 1;
        const bool pvalid = (p + 1 < NP) && (zn >= 0) && (zn < D_);

        // issue global prefetch early: latency spans h-phase + w-phase
        float pv[NSEC];
        if (pvalid) {
            const float* xp = xb + (size_t)zn * HW_;
#pragma unroll
            for (int k = 0; k < NSEC; ++k) pv[k] = (goff[k] >= 0) ? xp[goff[k]] : 0.f;
        }

        // ================= phase 1: h-conv of plane p-1, merge-store =================
        if (hact && p >= 1) {
            const int ziq = z0 - 5 + p;
            // accumulate only while R holds a valid staged plane (p <= NP)
            if (p <= NP && ziq >= 0 && ziq < D_) {
                if (hA) hconv<0, 3>(Rm, hb, cg_, cz_, acc);
                else    hconv<3, 5>(Rm, hb, cg_, cz_, acc);
            }
            // store z = z0 + p - 10: A's pend (saved last region) + B's scratch
            if (p >= 10 && hA) {
                const float* sc = &scr[(((p - 1) & 1) * NITEM + hitem) * 8];
                float4 s0 = *(const float4*)&sc[0];
                float4 s1 = *(const float4*)&sc[4];
                float4 o0 = f4add(pend0, s0);
                float4 o1 = f4add(pend1, s1);
                int z = z0 + p - 10;
                size_t o = ((size_t)(b * D_ + z) * H_ + (h0 + 2 * hq)) * W_ + (w0 + 4 * hcg);
                *(float4*)&out[o] = o0;
                *(float4*)&out[o + W_] = o1;
            }
            // capture leaving slot (z = z0 + p - 9), then shift ring
            float4 lv0 = acc[0][0], lv1 = acc[0][1];
#pragma unroll
            for (int k = 0; k < 8; ++k) { acc[k][0] = acc[k + 1][0]; acc[k][1] = acc[k + 1][1]; }
            acc[8][0] = make_float4(0.f, 0.f, 0.f, 0.f);
            acc[8][1] = make_float4(0.f, 0.f, 0.f, 0.f);
            if (p >= 9) {
                if (hA) { pend0 = lv0; pend1 = lv1; }
                else {
                    float* sc = &scr[((p & 1) * NITEM + hitem) * 8];
                    *(float4*)&sc[0] = lv0;
                    *(float4*)&sc[4] = lv1;
                }
            }
        }

        __syncthreads();   // B2: all R reads done; scratch reads done

        // ================= phase 2: w-conv of plane p -> R; stage plane p+1 =========
        if (p < NP && zi >= 0 && zi < D_) {
            const float* xt = xtb + (p & 1) * XT_SZ;
#pragma unroll
            for (int sec = 0; sec < 2; ++sec) {
                if (sec == 1 && !sec1) break;
                const int wb = sec ? wb1 : wb0;
                const int rw = sec ? rw1 : rw0;
                float win[20];
                {
                    const float4* p4 = (const float4*)&xt[wb];
#pragma unroll
                    for (int q = 0; q < 5; ++q) {
                        float4 a = p4[q];
                        win[4 * q] = a.x; win[4 * q + 1] = a.y;
                        win[4 * q + 2] = a.z; win[4 * q + 3] = a.w;
                    }
                }
                float cj[4], sp[4][7];
#pragma unroll
                for (int j = 0; j < 4; ++j) {
                    cj[j] = win[j + 7];
#pragma unroll
                    for (int k = 1; k <= 7; ++k) sp[j][k - 1] = win[j + 7 - k] + win[j + 7 + k];
                }
#pragma unroll
                for (int n = 0; n < NT; ++n) {
                    float4 a;
                    a.x = cg_[n][0] * cj[0]; a.y = cg_[n][0] * cj[1];
                    a.z = cg_[n][0] * cj[2]; a.w = cg_[n][0] * cj[3];
#pragma unroll
                    for (int k = 1; k <= 7; ++k) {
                        float c = cg_[n][k];
                        a.x = fmaf(c, sp[0][k - 1], a.x);
                        a.y = fmaf(c, sp[1][k - 1], a.y);
                        a.z = fmaf(c, sp[2][k - 1], a.z);
                        a.w = fmaf(c, sp[3][k - 1], a.w);
                    }
                    *(float4*)&Rm[n * CTERM + rw] = a;
                }
            }
        }
        // write prefetched plane p+1 into xt[(p+1)&1]
        if (pvalid) {
            float* xn = xtb + ((p + 1) & 1) * XT_SZ;
#pragma unroll
            for (int k = 0; k < NSEC; ++k) xn[loff[k]] = pv[k];
        }
    }
}

extern "C" void kernel_launch(void* const* d_in, const int* in_sizes, int n_in,
                              void* d_out, int out_size, void* d_ws, size_t ws_size,
                              hipStream_t stream) {
    const float* x      = (const float*)d_in[0];
    const float* bet_xy = (const float*)d_in[1];
    const float* bet_z  = (const float*)d_in[2];
    const float* alpha  = (const float*)d_in[3];
    float* out = (float*)d_out;

    hipLaunchKernelGGL(conv_kernel, dim3(W_ / TW, H_ / TH, B_ * (D_ / ZCHUNK)),
                       dim3(NTHR), 0, stream, x, bet_xy, bet_z, alpha, out);
}